// Round 19
// baseline (172.280 us; speedup 1.0000x reference)
//
#include <hip/hip_runtime.h>

typedef unsigned short u16;
using bf16x8 = __attribute__((ext_vector_type(8))) __bf16;
using f32x4  = __attribute__((ext_vector_type(4))) float;
using u16x8  = __attribute__((ext_vector_type(8))) unsigned short;
using u16x4  = __attribute__((ext_vector_type(4))) unsigned short;

#define SEQ   2048
#define HID   1024
#define NHEAD 16
#define HD    64
#define BATCH 2
#define NTOK  4096   // BATCH*SEQ

__device__ __forceinline__ u16 f2bf(float f) {
  unsigned u = __builtin_bit_cast(unsigned, f);
  u += 0x7fffu + ((u >> 16) & 1u);
  return (u16)(u >> 16);
}
__device__ __forceinline__ float bf2f(u16 v) {
  unsigned u = ((unsigned)v) << 16;
  return __builtin_bit_cast(float, u);
}

__device__ __forceinline__ void gld_lds16(const void* g, void* l) {
  __builtin_amdgcn_global_load_lds(
      (__attribute__((address_space(1))) void*)(__UINTPTR_TYPE__)g,
      (__attribute__((address_space(3))) void*)l, 16, 0, 0);
}

// pack two f32 -> two bf16 (RNE) in one VALU op
__device__ __forceinline__ unsigned cvtpk(float lo, float hi) {
  unsigned r;
  asm("v_cvt_pk_bf16_f32 %0, %1, %2" : "=v"(r) : "v"(lo), "v"(hi));
  return r;
}

// VALU-pipe cross-lane rotate within a 16-lane DPP row
template<int CTRL>
__device__ __forceinline__ float row_ror(float x) {
  int xi = __builtin_bit_cast(int, x);
  int r  = __builtin_amdgcn_update_dpp(xi, xi, CTRL, 0xf, 0xf, false);
  return __builtin_bit_cast(float, r);
}
__device__ __forceinline__ float rowmax16(float x) {
  x = fmaxf(x, row_ror<0x121>(x));
  x = fmaxf(x, row_ror<0x122>(x));
  x = fmaxf(x, row_ror<0x124>(x));
  x = fmaxf(x, row_ror<0x128>(x));
  return x;
}
__device__ __forceinline__ float rowsum16(float x) {
  x += row_ror<0x121>(x);
  x += row_ror<0x122>(x);
  x += row_ror<0x124>(x);
  x += row_ror<0x128>(x);
  return x;
}

// ---------------- fused fp32 -> bf16 convert (X, Wqkv, Wo in one launch) ----
__global__ __launch_bounds__(256) void cvt3_kernel(const float* __restrict__ a, u16* __restrict__ oa,
                                                   const float* __restrict__ b, u16* __restrict__ ob,
                                                   const float* __restrict__ c, u16* __restrict__ oc) {
  const float* in; u16* out; int off;
  int bid = blockIdx.x;
  if (bid < 4096)      { in = a; out = oa; off = bid; }
  else if (bid < 7168) { in = b; out = ob; off = bid - 4096; }
  else                 { in = c; out = oc; off = bid - 7168; }
  int i = (off * 256 + threadIdx.x) * 4;
  float4 v = *reinterpret_cast<const float4*>(in + i);
  u16x4 o = { f2bf(v.x), f2bf(v.y), f2bf(v.z), f2bf(v.w) };
  *reinterpret_cast<u16x4*>(out + i) = o;
}

// ---------------- GEMM: C[M,N] = A[M,K] * B[N,K]^T, 128x128 ----------------
// V-range blocks (bn >= 16) compute the transposed tile via operand swap and
// write straight to VT[b,h][d][tok].
template<bool BF16OUT>
__global__ __launch_bounds__(256) void gemm_bt(const u16* __restrict__ A,
                                               const u16* __restrict__ B,
                                               void* __restrict__ Cv,
                                               u16* __restrict__ VT,
                                               int M, int N, int K) {
  __shared__ u16 At[128 * 64];
  __shared__ u16 Bt[128 * 64];
  const int tid  = threadIdx.x;
  const int wave = tid >> 6;
  const int lane = tid & 63;
  const int g    = lane >> 4;
  const int r16  = lane & 15;
  const int wr   = wave >> 1;
  const int wc   = wave & 1;
  const int bm   = blockIdx.y;
  const int bn   = blockIdx.x;
  const bool isV = (VT != nullptr) && (bn >= 16);

  const u16* Ab = A + (size_t)bm * 128 * K;
  const u16* Bb = B + (size_t)bn * 128 * K;
  const int srow = lane >> 3;
  const int scol = (lane & 7) * 8;

  f32x4 acc[4][4] = {};

  for (int kt = 0; kt < K; kt += 64) {
#pragma unroll
    for (int c = 0; c < 4; ++c) {
      int seg = wave * 4 + c;
      gld_lds16(Ab + (size_t)(seg * 8 + srow) * K + kt + scol, &At[seg * 512]);
      gld_lds16(Bb + (size_t)(seg * 8 + srow) * K + kt + scol, &Bt[seg * 512]);
    }
    __syncthreads();
#pragma unroll
    for (int ko = 0; ko < 64; ko += 32) {
      bf16x8 af[4], bfr[4];
#pragma unroll
      for (int mi = 0; mi < 4; ++mi)
        af[mi] = *reinterpret_cast<const bf16x8*>(&At[(wr * 64 + mi * 16 + r16) * 64 + ko + g * 8]);
#pragma unroll
      for (int ni = 0; ni < 4; ++ni)
        bfr[ni] = *reinterpret_cast<const bf16x8*>(&Bt[(wc * 64 + ni * 16 + r16) * 64 + ko + g * 8]);
      if (isV) {
#pragma unroll
        for (int mi = 0; mi < 4; ++mi)
#pragma unroll
          for (int ni = 0; ni < 4; ++ni)
            acc[ni][mi] = __builtin_amdgcn_mfma_f32_16x16x32_bf16(bfr[ni], af[mi], acc[ni][mi], 0, 0, 0);
      } else {
#pragma unroll
        for (int mi = 0; mi < 4; ++mi)
#pragma unroll
          for (int ni = 0; ni < 4; ++ni)
            acc[mi][ni] = __builtin_amdgcn_mfma_f32_16x16x32_bf16(af[mi], bfr[ni], acc[mi][ni], 0, 0, 0);
      }
    }
    __syncthreads();
  }

  if (isV) {
#pragma unroll
    for (int a = 0; a < 4; ++a)
#pragma unroll
      for (int c = 0; c < 4; ++c) {
#pragma unroll
        for (int r = 0; r < 4; ++r) {
          int hh   = (bn - 16) * 128 + wc * 64 + a * 16 + g * 4 + r;
          int tokg = bm * 128 + wr * 64 + c * 16 + r16;
          int b_   = tokg >> 11;
          int tok  = tokg & (SEQ - 1);
          int h_   = hh >> 6;
          int d_   = hh & 63;
          VT[((size_t)(b_ * NHEAD + h_) * HD + d_) * SEQ + tok] = f2bf(acc[a][c][r]);
        }
      }
  } else {
#pragma unroll
    for (int mi = 0; mi < 4; ++mi)
#pragma unroll
      for (int ni = 0; ni < 4; ++ni) {
        int row0 = bm * 128 + wr * 64 + mi * 16 + g * 4;
        int col  = bn * 128 + wc * 64 + ni * 16 + r16;
#pragma unroll
        for (int r = 0; r < 4; ++r) {
          float v = acc[mi][ni][r];
          if (BF16OUT) ((u16*)Cv)[(size_t)(row0 + r) * N + col] = f2bf(v);
          else         ((float*)Cv)[(size_t)(row0 + r) * N + col] = v;
        }
      }
  }
}

// ---------------- GEMM: 128x64 tile (O-proj: grid 512 = 2 blocks/CU) ----
__global__ __launch_bounds__(256) void gemm_bt64(const u16* __restrict__ A,
                                                 const u16* __restrict__ B,
                                                 float* __restrict__ C,
                                                 int M, int N, int K) {
  __shared__ u16 At[128 * 64];
  __shared__ u16 Bt[64 * 64];
  const int tid  = threadIdx.x;
  const int wave = tid >> 6;
  const int lane = tid & 63;
  const int g    = lane >> 4;
  const int r16  = lane & 15;
  const int bm   = blockIdx.y;
  const int bn   = blockIdx.x;

  const u16* Ab = A + (size_t)bm * 128 * K;
  const u16* Bb = B + (size_t)bn * 64 * K;
  const int srow = lane >> 3;
  const int scol = (lane & 7) * 8;

  f32x4 acc[2][4] = {};

  for (int kt = 0; kt < K; kt += 64) {
#pragma unroll
    for (int c = 0; c < 4; ++c) {
      int seg = wave * 4 + c;
      gld_lds16(Ab + (size_t)(seg * 8 + srow) * K + kt + scol, &At[seg * 512]);
    }
#pragma unroll
    for (int c = 0; c < 2; ++c) {
      int seg = wave * 2 + c;
      gld_lds16(Bb + (size_t)(seg * 8 + srow) * K + kt + scol, &Bt[seg * 512]);
    }
    __syncthreads();
#pragma unroll
    for (int ko = 0; ko < 64; ko += 32) {
      bf16x8 af[2], bfr[4];
#pragma unroll
      for (int mi = 0; mi < 2; ++mi)
        af[mi] = *reinterpret_cast<const bf16x8*>(&At[(wave * 32 + mi * 16 + r16) * 64 + ko + g * 8]);
#pragma unroll
      for (int ni = 0; ni < 4; ++ni)
        bfr[ni] = *reinterpret_cast<const bf16x8*>(&Bt[(ni * 16 + r16) * 64 + ko + g * 8]);
#pragma unroll
      for (int mi = 0; mi < 2; ++mi)
#pragma unroll
        for (int ni = 0; ni < 4; ++ni)
          acc[mi][ni] = __builtin_amdgcn_mfma_f32_16x16x32_bf16(af[mi], bfr[ni], acc[mi][ni], 0, 0, 0);
    }
    __syncthreads();
  }

#pragma unroll
  for (int mi = 0; mi < 2; ++mi)
#pragma unroll
    for (int ni = 0; ni < 4; ++ni) {
      int row0 = bm * 128 + wave * 32 + mi * 16 + g * 4;
      int col  = bn * 64 + ni * 16 + r16;
#pragma unroll
      for (int r = 0; r < 4; ++r)
        C[(size_t)(row0 + r) * N + col] = acc[mi][ni][r];
    }
}

// ---------------- flash attention: 8-wave blocks (128 q) + KV-split-2 ----------------
// Inner math identical to the verified R17 kernel; per-wave LDS 10K -> 6K
// (K/V staging shared by 8 waves, one gld_lds/lane). 1024 blocks, 48KB LDS
// -> 3 blocks/CU x 8 waves = 24 waves/CU. half = n>>9 does KV [half*1024,+1024).
// Partials: half0 -> P0 (AOb, stride 1024); half1 -> QKVb dead V-slots
// (stride 3072). (m,l) to ML. Merge kernel combines into P0.
__global__ __launch_bounds__(512) void attn_kernel(const u16* __restrict__ qkv,
                                                   const u16* __restrict__ VT,
                                                   const float* __restrict__ mask,
                                                   u16* __restrict__ P0,
                                                   u16* __restrict__ P1,
                                                   float* __restrict__ ML) {
  __shared__ u16 Kt[2][64 * 64];   // 16K
  __shared__ u16 Vt[2][64 * 64];   // 16K
  __shared__ u16 Pl[8][16 * 64];   // 16K (wave-private)

  const int tid  = threadIdx.x;
  const int w    = tid >> 6;          // 0..7
  const int lane = tid & 63;
  const int g    = lane >> 4;
  const int r16  = lane & 15;

  const int n0   = blockIdx.x;
  const int half = n0 >> 9;
  const int n    = n0 & 511;
  const int kv0  = half << 10;
  const int KVEND = kv0 + 1024;

  const int x  = n & 7;
  const int s_ = n >> 3;
  const int h  = s_ & 15;
  const int t_ = ((s_ >> 4) << 3) + x;   // 0..31
  const int b  = t_ >> 4;
  const int qt = t_ & 15;                // 128-row q tiles

  const size_t tokbase = (size_t)b * SEQ;
  const u16* VTbh = VT + (size_t)(b * NHEAD + h) * HD * SEQ;

  bf16x8 aq[2];
  {
    int qrow = qt * 128 + w * 16 + r16;
#pragma unroll
    for (int ko = 0; ko < 2; ++ko)
      aq[ko] = *reinterpret_cast<const bf16x8*>(
          qkv + ((tokbase + qrow) * 3 + 0) * HID + h * HD + ko * 32 + g * 8);
  }

  f32x4 o[4] = {};
  float mrow[4], lrow[4];
#pragma unroll
  for (int r = 0; r < 4; ++r) { mrow[r] = -3.0e38f; lrow[r] = 0.f; }

  const int srowK = lane >> 3;        // 0..7

  // wave w stages seg w (rows 8w..8w+7); one gld_lds per lane
#define STAGE_K(buf, kb)                                                        \
  {                                                                             \
    int sK  = ((w >> 1) + srowK) & 7;                                           \
    int srcc = (lane & 7) ^ sK;                                                 \
    gld_lds16(qkv + ((tokbase + (kb) + w * 8 + srowK) * 3 + 1) * HID +          \
                  h * HD + srcc * 8,                                            \
              &Kt[buf][w * 512]);                                               \
  }
#define STAGE_V(buf, kb)                                                        \
  {                                                                             \
    int sV  = ((w >> 1) + srowK) & 7;                                           \
    int srcc = (lane & 7) ^ sV;                                                 \
    gld_lds16(VTbh + (size_t)(w * 8 + srowK) * SEQ + (kb) + srcc * 8,           \
              &Vt[buf][w * 512]);                                               \
  }

  // ---- prologue: K+V tile 0 in flight ----
  STAGE_K(0, kv0);
  STAGE_V(0, kv0);

#pragma unroll 1
  for (int kb = kv0; kb < KVEND; kb += 64) {
    const int cur = (kb >> 6) & 1;
    const int nxt = cur ^ 1;
    const bool more = (kb + 64) < KVEND;

    // ---- mask regs for THIS tile ----
    float mpre[4][4];
#pragma unroll
    for (int r = 0; r < 4; ++r) {
      int q = qt * 128 + w * 16 + g * 4 + r;
      const float* mp = mask + ((size_t)b * SEQ + q) * SEQ + kb;
#pragma unroll
      for (int ni = 0; ni < 4; ++ni) mpre[r][ni] = mp[ni * 16 + r16];
    }

    __syncthreads();   // Kt/Vt[cur] + mask landed; all waves done with [nxt]

    // ---- S = Q K^T on Kt[cur] ----
    f32x4 sf[4] = {};
    __builtin_amdgcn_s_setprio(1);
#pragma unroll
    for (int ko = 0; ko < 2; ++ko) {
      bf16x8 bk[4];
#pragma unroll
      for (int ni = 0; ni < 4; ++ni) {
        int row = ni * 16 + r16;
        int sK  = (ni + (r16 & 7)) & 7;
        bk[ni] = *reinterpret_cast<const bf16x8*>(
            &Kt[cur][row * 64 + (((ko * 4 + g) ^ sK) << 3)]);
      }
#pragma unroll
      for (int ni = 0; ni < 4; ++ni)
        sf[ni] = __builtin_amdgcn_mfma_f32_16x16x32_bf16(aq[ko], bk[ni], sf[ni], 0, 0, 0);
    }
    __builtin_amdgcn_s_setprio(0);

    // ---- online softmax: DPP rotate-reduce + defer-max (THR=8) ----
    float mx[4];
#pragma unroll
    for (int r = 0; r < 4; ++r) {
      float m_ = -3.0e38f;
#pragma unroll
      for (int ni = 0; ni < 4; ++ni) {
        float sv = sf[ni][r] * 0.125f + mpre[r][ni];
        sf[ni][r] = sv;
        m_ = fmaxf(m_, sv);
      }
      mx[r] = rowmax16(m_);
    }
    float need = 0.f;
#pragma unroll
    for (int r = 0; r < 4; ++r) need = fmaxf(need, mx[r] - mrow[r]);
    if (__any(need > 8.0f)) {
#pragma unroll
      for (int r = 0; r < 4; ++r) {
        float mnew  = fmaxf(mrow[r], mx[r]);
        float alpha = __expf(mrow[r] - mnew);
        mrow[r] = mnew;
        lrow[r] *= alpha;
#pragma unroll
        for (int di = 0; di < 4; ++di) o[di][r] *= alpha;
      }
    }
#pragma unroll
    for (int r = 0; r < 4; ++r) {
      float p0 = __expf(sf[0][r] - mrow[r]);
      float p1 = __expf(sf[1][r] - mrow[r]);
      float p2 = __expf(sf[2][r] - mrow[r]);
      float p3 = __expf(sf[3][r] - mrow[r]);
      float s  = rowsum16(p0 + p1 + p2 + p3);
      lrow[r] += s;
      unsigned pk01 = cvtpk(p0, p1);
      unsigned pk23 = cvtpk(p2, p3);
      int prow = g * 4 + r;
      int sP   = prow & 7;
      u16 pv[4] = { (u16)pk01, (u16)(pk01 >> 16), (u16)pk23, (u16)(pk23 >> 16) };
#pragma unroll
      for (int ni = 0; ni < 4; ++ni) {
        int chunk = ni * 2 + (r16 >> 3);
        Pl[w][prow * 64 + ((chunk ^ sP) << 3) + (r16 & 7)] = pv[ni];
      }
    }
    // no barrier: Pl[w] is wave-private; lgkmcnt orders write->read

    // ---- prefetch next K+V tiles (zero-register) ----
    if (more) { STAGE_K(nxt, kb + 64); STAGE_V(nxt, kb + 64); }

    // ---- O += P V ----
    __builtin_amdgcn_s_setprio(1);
#pragma unroll
    for (int kk = 0; kk < 2; ++kk) {
      bf16x8 pa, bv[4];
      pa = *reinterpret_cast<const bf16x8*>(
          &Pl[w][r16 * 64 + (((kk * 4 + g) ^ (r16 & 7)) << 3)]);
#pragma unroll
      for (int di = 0; di < 4; ++di) {
        int row = di * 16 + r16;
        int sV  = (di + (r16 & 7)) & 7;
        bv[di] = *reinterpret_cast<const bf16x8*>(
            &Vt[cur][row * 64 + (((kk * 4 + g) ^ sV) << 3)]);
      }
#pragma unroll
      for (int di = 0; di < 4; ++di)
        o[di] = __builtin_amdgcn_mfma_f32_16x16x32_bf16(pa, bv[di], o[di], 0, 0, 0);
    }
    __builtin_amdgcn_s_setprio(0);
  }

  // ---- finalize: normalized partial O; (m,l) to ML ----
#pragma unroll
  for (int di = 0; di < 4; ++di)
#pragma unroll
    for (int r = 0; r < 4; ++r) {
      int srow = qt * 128 + w * 16 + g * 4 + r;
      size_t idx = tokbase + srow;
      float val = o[di][r] / lrow[r];
      u16 bv = f2bf(val);
      if (half == 0) P0[idx * HID + h * HD + di * 16 + r16] = bv;
      else           P1[(idx * 3 + 2) * HID + h * HD + di * 16 + r16] = bv;
    }
  if (r16 == 0) {
#pragma unroll
    for (int r = 0; r < 4; ++r) {
      int srow = qt * 128 + w * 16 + g * 4 + r;
      size_t mi_ = ((tokbase + srow) * NHEAD + h) * 4 + half * 2;
      ML[mi_ + 0] = mrow[r];
      ML[mi_ + 1] = lrow[r];
    }
  }
#undef STAGE_K
#undef STAGE_V
}

// ---------------- flash-combine of the two KV halves (in place into P0) ----
// P1 lives in QKVb's dead V-slots: token stride 3*HID.
__global__ __launch_bounds__(256) void merge_kernel(u16* __restrict__ P0,
                                                    const u16* __restrict__ P1,
                                                    const float* __restrict__ ML) {
  int t  = blockIdx.x * 256 + threadIdx.x;
  int i  = t >> 3;                 // tok*16 + h
  int d0 = (t & 7) * 8;
  int tok = i >> 4, h = i & 15;
  size_t off0 = (size_t)tok * HID + h * 64 + d0;
  size_t off1 = ((size_t)tok * 3 + 2) * HID + h * 64 + d0;
  float m0 = ML[(size_t)i * 4 + 0], l0 = ML[(size_t)i * 4 + 1];
  float m1 = ML[(size_t)i * 4 + 2], l1 = ML[(size_t)i * 4 + 3];
  float ms = fmaxf(m0, m1);
  float w0 = l0 * __expf(m0 - ms);
  float w1 = l1 * __expf(m1 - ms);
  float inv = 1.0f / (w0 + w1);
  w0 *= inv; w1 *= inv;
  u16x8 a = *reinterpret_cast<const u16x8*>(P0 + off0);
  u16x8 c = *reinterpret_cast<const u16x8*>(P1 + off1);
  u16x8 o;
#pragma unroll
  for (int j = 0; j < 8; ++j)
    o[j] = f2bf(w0 * bf2f((u16)a[j]) + w1 * bf2f((u16)c[j]));
  *reinterpret_cast<u16x8*>(P0 + off0) = o;
}

// ---------------- launcher ----------------
extern "C" void kernel_launch(void* const* d_in, const int* in_sizes, int n_in,
                              void* d_out, int out_size, void* d_ws, size_t ws_size,
                              hipStream_t stream) {
  (void)in_sizes; (void)n_in; (void)out_size; (void)ws_size;
  const float* hs   = (const float*)d_in[0];
  const float* mask = (const float*)d_in[1];
  const float* wqkv = (const float*)d_in[2];
  const float* wo   = (const float*)d_in[3];
  float* out = (float*)d_out;

  char* ws   = (char*)d_ws;
  u16* Xb    = (u16*)(ws);                        // 8 MiB
  u16* Wqkvb = (u16*)(ws + 8u  * 1024 * 1024);    // 6 MiB
  u16* Wob   = (u16*)(ws + 14u * 1024 * 1024);    // 2 MiB
  u16* QKVb  = (u16*)(ws + 16u * 1024 * 1024);    // 24 MiB (V slots reused as P1)
  u16* AOb   = (u16*)(ws + 40u * 1024 * 1024);    // 8 MiB (P0 / final AO)
  u16* VT    = (u16*)(ws + 48u * 1024 * 1024);    // 8 MiB
  float* ML  = (float*)(ws + 56u * 1024 * 1024);  // 1 MiB (ws >= 57 MiB verified R13)

  cvt3_kernel<<<8192, 256, 0, stream>>>(hs, Xb, wqkv, Wqkvb, wo, Wob);

  gemm_bt<true><<<dim3(3072 / 128, 4096 / 128), 256, 0, stream>>>(Xb, Wqkvb, QKVb, VT, NTOK, 3072, HID);
  attn_kernel  <<<1024, 512, 0, stream>>>(QKVb, VT, mask, AOb, QKVb, ML);
  merge_kernel <<<2048, 256, 0, stream>>>(AOb, QKVb, ML);
  gemm_bt64    <<<dim3(1024 / 64, 4096 / 128), 256, 0, stream>>>(AOb, Wob, out, NTOK, 1024, HID);
}

// Round 21
// 169.230 us; speedup vs baseline: 1.0180x; 1.0180x over previous
//
#include <hip/hip_runtime.h>

typedef unsigned short u16;
using bf16x8 = __attribute__((ext_vector_type(8))) __bf16;
using f32x4  = __attribute__((ext_vector_type(4))) float;
using u16x8  = __attribute__((ext_vector_type(8))) unsigned short;
using u16x4  = __attribute__((ext_vector_type(4))) unsigned short;

#define SEQ   2048
#define HID   1024
#define NHEAD 16
#define HD    64
#define BATCH 2
#define NTOK  4096   // BATCH*SEQ

__device__ __forceinline__ u16 f2bf(float f) {
  unsigned u = __builtin_bit_cast(unsigned, f);
  u += 0x7fffu + ((u >> 16) & 1u);
  return (u16)(u >> 16);
}

__device__ __forceinline__ void gld_lds16(const void* g, void* l) {
  __builtin_amdgcn_global_load_lds(
      (__attribute__((address_space(1))) void*)(__UINTPTR_TYPE__)g,
      (__attribute__((address_space(3))) void*)l, 16, 0, 0);
}

// pack two f32 -> two bf16 (RNE) in one VALU op
__device__ __forceinline__ unsigned cvtpk(float lo, float hi) {
  unsigned r;
  asm("v_cvt_pk_bf16_f32 %0, %1, %2" : "=v"(r) : "v"(lo), "v"(hi));
  return r;
}

// VALU-pipe cross-lane rotate within a 16-lane DPP row
template<int CTRL>
__device__ __forceinline__ float row_ror(float x) {
  int xi = __builtin_bit_cast(int, x);
  int r  = __builtin_amdgcn_update_dpp(xi, xi, CTRL, 0xf, 0xf, false);
  return __builtin_bit_cast(float, r);
}
__device__ __forceinline__ float rowmax16(float x) {
  x = fmaxf(x, row_ror<0x121>(x));
  x = fmaxf(x, row_ror<0x122>(x));
  x = fmaxf(x, row_ror<0x124>(x));
  x = fmaxf(x, row_ror<0x128>(x));
  return x;
}
__device__ __forceinline__ float rowsum16(float x) {
  x += row_ror<0x121>(x);
  x += row_ror<0x122>(x);
  x += row_ror<0x124>(x);
  x += row_ror<0x128>(x);
  return x;
}

// ---------------- fused fp32 -> bf16 convert (X, Wqkv, Wo in one launch) ----
__global__ __launch_bounds__(256) void cvt3_kernel(const float* __restrict__ a, u16* __restrict__ oa,
                                                   const float* __restrict__ b, u16* __restrict__ ob,
                                                   const float* __restrict__ c, u16* __restrict__ oc) {
  const float* in; u16* out; int off;
  int bid = blockIdx.x;
  if (bid < 4096)      { in = a; out = oa; off = bid; }
  else if (bid < 7168) { in = b; out = ob; off = bid - 4096; }
  else                 { in = c; out = oc; off = bid - 7168; }
  int i = (off * 256 + threadIdx.x) * 4;
  float4 v = *reinterpret_cast<const float4*>(in + i);
  u16x4 o = { f2bf(v.x), f2bf(v.y), f2bf(v.z), f2bf(v.w) };
  *reinterpret_cast<u16x4*>(out + i) = o;
}

// ---------------- GEMM: C[M,N] = A[M,K] * B[N,K]^T, 128x128 ----------------
// V-range blocks (bn >= 16) compute the transposed tile via operand swap and
// write straight to VT[b,h][d][tok].
template<bool BF16OUT>
__global__ __launch_bounds__(256) void gemm_bt(const u16* __restrict__ A,
                                               const u16* __restrict__ B,
                                               void* __restrict__ Cv,
                                               u16* __restrict__ VT,
                                               int M, int N, int K) {
  __shared__ u16 At[128 * 64];
  __shared__ u16 Bt[128 * 64];
  const int tid  = threadIdx.x;
  const int wave = tid >> 6;
  const int lane = tid & 63;
  const int g    = lane >> 4;
  const int r16  = lane & 15;
  const int wr   = wave >> 1;
  const int wc   = wave & 1;
  const int bm   = blockIdx.y;
  const int bn   = blockIdx.x;
  const bool isV = (VT != nullptr) && (bn >= 16);

  const u16* Ab = A + (size_t)bm * 128 * K;
  const u16* Bb = B + (size_t)bn * 128 * K;
  const int srow = lane >> 3;
  const int scol = (lane & 7) * 8;

  f32x4 acc[4][4] = {};

  for (int kt = 0; kt < K; kt += 64) {
#pragma unroll
    for (int c = 0; c < 4; ++c) {
      int seg = wave * 4 + c;
      gld_lds16(Ab + (size_t)(seg * 8 + srow) * K + kt + scol, &At[seg * 512]);
      gld_lds16(Bb + (size_t)(seg * 8 + srow) * K + kt + scol, &Bt[seg * 512]);
    }
    __syncthreads();
#pragma unroll
    for (int ko = 0; ko < 64; ko += 32) {
      bf16x8 af[4], bfr[4];
#pragma unroll
      for (int mi = 0; mi < 4; ++mi)
        af[mi] = *reinterpret_cast<const bf16x8*>(&At[(wr * 64 + mi * 16 + r16) * 64 + ko + g * 8]);
#pragma unroll
      for (int ni = 0; ni < 4; ++ni)
        bfr[ni] = *reinterpret_cast<const bf16x8*>(&Bt[(wc * 64 + ni * 16 + r16) * 64 + ko + g * 8]);
      if (isV) {
#pragma unroll
        for (int mi = 0; mi < 4; ++mi)
#pragma unroll
          for (int ni = 0; ni < 4; ++ni)
            acc[ni][mi] = __builtin_amdgcn_mfma_f32_16x16x32_bf16(bfr[ni], af[mi], acc[ni][mi], 0, 0, 0);
      } else {
#pragma unroll
        for (int mi = 0; mi < 4; ++mi)
#pragma unroll
          for (int ni = 0; ni < 4; ++ni)
            acc[mi][ni] = __builtin_amdgcn_mfma_f32_16x16x32_bf16(af[mi], bfr[ni], acc[mi][ni], 0, 0, 0);
      }
    }
    __syncthreads();
  }

  if (isV) {
#pragma unroll
    for (int a = 0; a < 4; ++a)
#pragma unroll
      for (int c = 0; c < 4; ++c) {
#pragma unroll
        for (int r = 0; r < 4; ++r) {
          int hh   = (bn - 16) * 128 + wc * 64 + a * 16 + g * 4 + r;
          int tokg = bm * 128 + wr * 64 + c * 16 + r16;
          int b_   = tokg >> 11;
          int tok  = tokg & (SEQ - 1);
          int h_   = hh >> 6;
          int d_   = hh & 63;
          VT[((size_t)(b_ * NHEAD + h_) * HD + d_) * SEQ + tok] = f2bf(acc[a][c][r]);
        }
      }
  } else {
#pragma unroll
    for (int mi = 0; mi < 4; ++mi)
#pragma unroll
      for (int ni = 0; ni < 4; ++ni) {
        int row0 = bm * 128 + wr * 64 + mi * 16 + g * 4;
        int col  = bn * 128 + wc * 64 + ni * 16 + r16;
#pragma unroll
        for (int r = 0; r < 4; ++r) {
          float v = acc[mi][ni][r];
          if (BF16OUT) ((u16*)Cv)[(size_t)(row0 + r) * N + col] = f2bf(v);
          else         ((float*)Cv)[(size_t)(row0 + r) * N + col] = v;
        }
      }
  }
}

// ---------------- GEMM: 128x64 tile (O-proj: grid 512 = 2 blocks/CU) ----
__global__ __launch_bounds__(256) void gemm_bt64(const u16* __restrict__ A,
                                                 const u16* __restrict__ B,
                                                 float* __restrict__ C,
                                                 int M, int N, int K) {
  __shared__ u16 At[128 * 64];
  __shared__ u16 Bt[64 * 64];
  const int tid  = threadIdx.x;
  const int wave = tid >> 6;
  const int lane = tid & 63;
  const int g    = lane >> 4;
  const int r16  = lane & 15;
  const int bm   = blockIdx.y;
  const int bn   = blockIdx.x;

  const u16* Ab = A + (size_t)bm * 128 * K;
  const u16* Bb = B + (size_t)bn * 64 * K;
  const int srow = lane >> 3;
  const int scol = (lane & 7) * 8;

  f32x4 acc[2][4] = {};

  for (int kt = 0; kt < K; kt += 64) {
#pragma unroll
    for (int c = 0; c < 4; ++c) {
      int seg = wave * 4 + c;
      gld_lds16(Ab + (size_t)(seg * 8 + srow) * K + kt + scol, &At[seg * 512]);
    }
#pragma unroll
    for (int c = 0; c < 2; ++c) {
      int seg = wave * 2 + c;
      gld_lds16(Bb + (size_t)(seg * 8 + srow) * K + kt + scol, &Bt[seg * 512]);
    }
    __syncthreads();
#pragma unroll
    for (int ko = 0; ko < 64; ko += 32) {
      bf16x8 af[2], bfr[4];
#pragma unroll
      for (int mi = 0; mi < 2; ++mi)
        af[mi] = *reinterpret_cast<const bf16x8*>(&At[(wave * 32 + mi * 16 + r16) * 64 + ko + g * 8]);
#pragma unroll
      for (int ni = 0; ni < 4; ++ni)
        bfr[ni] = *reinterpret_cast<const bf16x8*>(&Bt[(ni * 16 + r16) * 64 + ko + g * 8]);
#pragma unroll
      for (int mi = 0; mi < 2; ++mi)
#pragma unroll
        for (int ni = 0; ni < 4; ++ni)
          acc[mi][ni] = __builtin_amdgcn_mfma_f32_16x16x32_bf16(af[mi], bfr[ni], acc[mi][ni], 0, 0, 0);
    }
    __syncthreads();
  }

#pragma unroll
  for (int mi = 0; mi < 2; ++mi)
#pragma unroll
    for (int ni = 0; ni < 4; ++ni) {
      int row0 = bm * 128 + wave * 32 + mi * 16 + g * 4;
      int col  = bn * 64 + ni * 16 + r16;
#pragma unroll
      for (int r = 0; r < 4; ++r)
        C[(size_t)(row0 + r) * N + col] = acc[mi][ni][r];
    }
}

// ---------------- flash attention (R17 verbatim: gld_lds K+V, 1 barrier/tile) ----
__global__ __launch_bounds__(256, 4) void attn_kernel(const u16* __restrict__ qkv,
                                                      const u16* __restrict__ VT,
                                                      const float* __restrict__ mask,
                                                      u16* __restrict__ AO) {
  __shared__ u16 Kt[2][64 * 64];   // [key][d] swizzled, double-buffered
  __shared__ u16 Vt[2][64 * 64];   // [d][key] swizzled, double-buffered
  __shared__ u16 Pl[4][16 * 64];   // per-wave P swizzled (wave-private)

  const int tid  = threadIdx.x;
  const int w    = tid >> 6;
  const int lane = tid & 63;
  const int g    = lane >> 4;
  const int r16  = lane & 15;

  const int n  = blockIdx.x;
  const int x  = n & 7;
  const int s_ = n >> 3;
  const int h  = s_ & 15;
  const int t_ = ((s_ >> 4) << 3) + x;
  const int b  = t_ >> 5;
  const int qt = t_ & 31;

  const size_t tokbase = (size_t)b * SEQ;
  const u16* VTbh = VT + (size_t)(b * NHEAD + h) * HD * SEQ;

  bf16x8 aq[2];
  {
    int qrow = qt * 64 + w * 16 + r16;
#pragma unroll
    for (int ko = 0; ko < 2; ++ko)
      aq[ko] = *reinterpret_cast<const bf16x8*>(
          qkv + ((tokbase + qrow) * 3 + 0) * HID + h * HD + ko * 32 + g * 8);
  }

  f32x4 o[4] = {};
  float mrow[4], lrow[4];
#pragma unroll
  for (int r = 0; r < 4; ++r) { mrow[r] = -3.0e38f; lrow[r] = 0.f; }

  const int srowK = lane >> 3;        // 0..7

#define STAGE_K(buf, kb)                                                        \
  {                                                                             \
    _Pragma("unroll")                                                           \
    for (int c = 0; c < 2; ++c) {                                               \
      int seg = w * 2 + c;                                                      \
      int sK  = ((seg >> 1) + srowK) & 7;                                       \
      int srcc = (lane & 7) ^ sK;                                               \
      gld_lds16(qkv + ((tokbase + (kb) + seg * 8 + srowK) * 3 + 1) * HID +      \
                    h * HD + srcc * 8,                                          \
                &Kt[buf][seg * 512]);                                           \
    }                                                                           \
  }
#define STAGE_V(buf, kb)                                                        \
  {                                                                             \
    _Pragma("unroll")                                                           \
    for (int c = 0; c < 2; ++c) {                                               \
      int seg = w * 2 + c;                                                      \
      int sV  = ((seg >> 1) + srowK) & 7;                                       \
      int srcc = (lane & 7) ^ sV;                                               \
      gld_lds16(VTbh + (size_t)(seg * 8 + srowK) * SEQ + (kb) + srcc * 8,       \
                &Vt[buf][seg * 512]);                                           \
    }                                                                           \
  }

  // ---- prologue: K+V tile 0 in flight ----
  STAGE_K(0, 0);
  STAGE_V(0, 0);

#pragma unroll 1
  for (int kb = 0; kb < SEQ; kb += 64) {
    const int cur = (kb >> 6) & 1;
    const int nxt = cur ^ 1;
    const bool more = (kb + 64) < SEQ;

    // ---- mask regs for THIS tile ----
    float mpre[4][4];
#pragma unroll
    for (int r = 0; r < 4; ++r) {
      int q = qt * 64 + w * 16 + g * 4 + r;
      const float* mp = mask + ((size_t)b * SEQ + q) * SEQ + kb;
#pragma unroll
      for (int ni = 0; ni < 4; ++ni) mpre[r][ni] = mp[ni * 16 + r16];
    }

    __syncthreads();   // Kt/Vt[cur] + mask landed; all waves done with [nxt] bufs

    // ---- S = Q K^T on Kt[cur] ----
    f32x4 sf[4] = {};
    __builtin_amdgcn_s_setprio(1);
#pragma unroll
    for (int ko = 0; ko < 2; ++ko) {
      bf16x8 bk[4];
#pragma unroll
      for (int ni = 0; ni < 4; ++ni) {
        int row = ni * 16 + r16;
        int sK  = (ni + (r16 & 7)) & 7;
        bk[ni] = *reinterpret_cast<const bf16x8*>(
            &Kt[cur][row * 64 + (((ko * 4 + g) ^ sK) << 3)]);
      }
#pragma unroll
      for (int ni = 0; ni < 4; ++ni)
        sf[ni] = __builtin_amdgcn_mfma_f32_16x16x32_bf16(aq[ko], bk[ni], sf[ni], 0, 0, 0);
    }
    __builtin_amdgcn_s_setprio(0);

    // ---- online softmax: DPP rotate-reduce + defer-max (THR=8) ----
    float mx[4];
#pragma unroll
    for (int r = 0; r < 4; ++r) {
      float m_ = -3.0e38f;
#pragma unroll
      for (int ni = 0; ni < 4; ++ni) {
        float sv = sf[ni][r] * 0.125f + mpre[r][ni];
        sf[ni][r] = sv;
        m_ = fmaxf(m_, sv);
      }
      mx[r] = rowmax16(m_);
    }
    float need = 0.f;
#pragma unroll
    for (int r = 0; r < 4; ++r) need = fmaxf(need, mx[r] - mrow[r]);
    if (__any(need > 8.0f)) {
#pragma unroll
      for (int r = 0; r < 4; ++r) {
        float mnew  = fmaxf(mrow[r], mx[r]);
        float alpha = __expf(mrow[r] - mnew);
        mrow[r] = mnew;
        lrow[r] *= alpha;
#pragma unroll
        for (int di = 0; di < 4; ++di) o[di][r] *= alpha;
      }
    }
#pragma unroll
    for (int r = 0; r < 4; ++r) {
      float p0 = __expf(sf[0][r] - mrow[r]);
      float p1 = __expf(sf[1][r] - mrow[r]);
      float p2 = __expf(sf[2][r] - mrow[r]);
      float p3 = __expf(sf[3][r] - mrow[r]);
      float s  = rowsum16(p0 + p1 + p2 + p3);
      lrow[r] += s;
      unsigned pk01 = cvtpk(p0, p1);
      unsigned pk23 = cvtpk(p2, p3);
      int prow = g * 4 + r;
      int sP   = prow & 7;
      u16 pv[4] = { (u16)pk01, (u16)(pk01 >> 16), (u16)pk23, (u16)(pk23 >> 16) };
#pragma unroll
      for (int ni = 0; ni < 4; ++ni) {
        int chunk = ni * 2 + (r16 >> 3);
        Pl[w][prow * 64 + ((chunk ^ sP) << 3) + (r16 & 7)] = pv[ni];
      }
    }
    // no barrier: Pl[w] is wave-private; lgkmcnt orders write->read

    // ---- prefetch next K+V tiles (zero-register) ----
    if (more) { STAGE_K(nxt, kb + 64); STAGE_V(nxt, kb + 64); }

    // ---- O += P V ----
    __builtin_amdgcn_s_setprio(1);
#pragma unroll
    for (int kk = 0; kk < 2; ++kk) {
      bf16x8 pa, bv[4];
      pa = *reinterpret_cast<const bf16x8*>(
          &Pl[w][r16 * 64 + (((kk * 4 + g) ^ (r16 & 7)) << 3)]);
#pragma unroll
      for (int di = 0; di < 4; ++di) {
        int row = di * 16 + r16;
        int sV  = (di + (r16 & 7)) & 7;
        bv[di] = *reinterpret_cast<const bf16x8*>(
            &Vt[cur][row * 64 + (((kk * 4 + g) ^ sV) << 3)]);
      }
#pragma unroll
      for (int di = 0; di < 4; ++di)
        o[di] = __builtin_amdgcn_mfma_f32_16x16x32_bf16(pa, bv[di], o[di], 0, 0, 0);
    }
    __builtin_amdgcn_s_setprio(0);
  }

  // finalize
#pragma unroll
  for (int di = 0; di < 4; ++di)
#pragma unroll
    for (int r = 0; r < 4; ++r) {
      int srow = qt * 64 + w * 16 + g * 4 + r;
      float val = o[di][r] / lrow[r];
      AO[(tokbase + srow) * HID + h * HD + di * 16 + r16] = f2bf(val);
    }
#undef STAGE_K
#undef STAGE_V
}

// ---------------- launcher ----------------
extern "C" void kernel_launch(void* const* d_in, const int* in_sizes, int n_in,
                              void* d_out, int out_size, void* d_ws, size_t ws_size,
                              hipStream_t stream) {
  (void)in_sizes; (void)n_in; (void)out_size; (void)ws_size;
  const float* hs   = (const float*)d_in[0];
  const float* mask = (const float*)d_in[1];
  const float* wqkv = (const float*)d_in[2];
  const float* wo   = (const float*)d_in[3];
  float* out = (float*)d_out;

  char* ws   = (char*)d_ws;
  u16* Xb    = (u16*)(ws);                        // 8 MiB
  u16* Wqkvb = (u16*)(ws + 8u  * 1024 * 1024);    // 6 MiB
  u16* Wob   = (u16*)(ws + 14u * 1024 * 1024);    // 2 MiB
  u16* QKVb  = (u16*)(ws + 16u * 1024 * 1024);    // 24 MiB (V range unused)
  u16* AOb   = (u16*)(ws + 40u * 1024 * 1024);    // 8 MiB
  u16* VT    = (u16*)(ws + 48u * 1024 * 1024);    // 8 MiB

  cvt3_kernel<<<8192, 256, 0, stream>>>(hs, Xb, wqkv, Wqkvb, wo, Wob);

  gemm_bt<true><<<dim3(3072 / 128, 4096 / 128), 256, 0, stream>>>(Xb, Wqkvb, QKVb, VT, NTOK, 3072, HID);
  attn_kernel  <<<1024, 256, 0, stream>>>(QKVb, VT, mask, AOb);
  gemm_bt64    <<<dim3(1024 / 64, 4096 / 128), 256, 0, stream>>>(AOb, Wob, out, NTOK, 1024, HID);
}

// Round 23
// 169.027 us; speedup vs baseline: 1.0192x; 1.0012x over previous
//
#include <hip/hip_runtime.h>

typedef unsigned short u16;
using bf16x8 = __attribute__((ext_vector_type(8))) __bf16;
using f32x4  = __attribute__((ext_vector_type(4))) float;
using u16x8  = __attribute__((ext_vector_type(8))) unsigned short;
using u16x4  = __attribute__((ext_vector_type(4))) unsigned short;

#define SEQ   2048
#define HID   1024
#define NHEAD 16
#define HD    64
#define BATCH 2
#define NTOK  4096   // BATCH*SEQ

__device__ __forceinline__ u16 f2bf(float f) {
  unsigned u = __builtin_bit_cast(unsigned, f);
  u += 0x7fffu + ((u >> 16) & 1u);
  return (u16)(u >> 16);
}

__device__ __forceinline__ void gld_lds16(const void* g, void* l) {
  __builtin_amdgcn_global_load_lds(
      (__attribute__((address_space(1))) void*)(__UINTPTR_TYPE__)g,
      (__attribute__((address_space(3))) void*)l, 16, 0, 0);
}

// pack two f32 -> two bf16 (RNE) in one VALU op
__device__ __forceinline__ unsigned cvtpk(float lo, float hi) {
  unsigned r;
  asm("v_cvt_pk_bf16_f32 %0, %1, %2" : "=v"(r) : "v"(lo), "v"(hi));
  return r;
}

// VALU-pipe cross-lane rotate within a 16-lane DPP row
template<int CTRL>
__device__ __forceinline__ float row_ror(float x) {
  int xi = __builtin_bit_cast(int, x);
  int r  = __builtin_amdgcn_update_dpp(xi, xi, CTRL, 0xf, 0xf, false);
  return __builtin_bit_cast(float, r);
}
__device__ __forceinline__ float rowmax16(float x) {
  x = fmaxf(x, row_ror<0x121>(x));
  x = fmaxf(x, row_ror<0x122>(x));
  x = fmaxf(x, row_ror<0x124>(x));
  x = fmaxf(x, row_ror<0x128>(x));
  return x;
}
__device__ __forceinline__ float rowsum16(float x) {
  x += row_ror<0x121>(x);
  x += row_ror<0x122>(x);
  x += row_ror<0x124>(x);
  x += row_ror<0x128>(x);
  return x;
}

// ---------------- fused fp32 -> bf16 convert (X, Wqkv, Wo in one launch) ----
__global__ __launch_bounds__(256) void cvt3_kernel(const float* __restrict__ a, u16* __restrict__ oa,
                                                   const float* __restrict__ b, u16* __restrict__ ob,
                                                   const float* __restrict__ c, u16* __restrict__ oc) {
  const float* in; u16* out; int off;
  int bid = blockIdx.x;
  if (bid < 4096)      { in = a; out = oa; off = bid; }
  else if (bid < 7168) { in = b; out = ob; off = bid - 4096; }
  else                 { in = c; out = oc; off = bid - 7168; }
  int i = (off * 256 + threadIdx.x) * 4;
  float4 v = *reinterpret_cast<const float4*>(in + i);
  u16x4 o = { f2bf(v.x), f2bf(v.y), f2bf(v.z), f2bf(v.w) };
  *reinterpret_cast<u16x4*>(out + i) = o;
}

// ---------------- GEMM: C[M,N] = A[M,K] * B[N,K]^T, 128x128 ----------------
// V-range blocks (bn >= 16) compute the transposed tile via operand swap and
// write straight to VT[b,h][d][tok].
template<bool BF16OUT>
__global__ __launch_bounds__(256) void gemm_bt(const u16* __restrict__ A,
                                               const u16* __restrict__ B,
                                               void* __restrict__ Cv,
                                               u16* __restrict__ VT,
                                               int M, int N, int K) {
  __shared__ u16 At[128 * 64];
  __shared__ u16 Bt[128 * 64];
  const int tid  = threadIdx.x;
  const int wave = tid >> 6;
  const int lane = tid & 63;
  const int g    = lane >> 4;
  const int r16  = lane & 15;
  const int wr   = wave >> 1;
  const int wc   = wave & 1;
  const int bm   = blockIdx.y;
  const int bn   = blockIdx.x;
  const bool isV = (VT != nullptr) && (bn >= 16);

  const u16* Ab = A + (size_t)bm * 128 * K;
  const u16* Bb = B + (size_t)bn * 128 * K;
  const int srow = lane >> 3;
  const int scol = (lane & 7) * 8;

  f32x4 acc[4][4] = {};

  for (int kt = 0; kt < K; kt += 64) {
#pragma unroll
    for (int c = 0; c < 4; ++c) {
      int seg = wave * 4 + c;
      gld_lds16(Ab + (size_t)(seg * 8 + srow) * K + kt + scol, &At[seg * 512]);
      gld_lds16(Bb + (size_t)(seg * 8 + srow) * K + kt + scol, &Bt[seg * 512]);
    }
    __syncthreads();
#pragma unroll
    for (int ko = 0; ko < 64; ko += 32) {
      bf16x8 af[4], bfr[4];
#pragma unroll
      for (int mi = 0; mi < 4; ++mi)
        af[mi] = *reinterpret_cast<const bf16x8*>(&At[(wr * 64 + mi * 16 + r16) * 64 + ko + g * 8]);
#pragma unroll
      for (int ni = 0; ni < 4; ++ni)
        bfr[ni] = *reinterpret_cast<const bf16x8*>(&Bt[(wc * 64 + ni * 16 + r16) * 64 + ko + g * 8]);
      if (isV) {
#pragma unroll
        for (int mi = 0; mi < 4; ++mi)
#pragma unroll
          for (int ni = 0; ni < 4; ++ni)
            acc[ni][mi] = __builtin_amdgcn_mfma_f32_16x16x32_bf16(bfr[ni], af[mi], acc[ni][mi], 0, 0, 0);
      } else {
#pragma unroll
        for (int mi = 0; mi < 4; ++mi)
#pragma unroll
          for (int ni = 0; ni < 4; ++ni)
            acc[mi][ni] = __builtin_amdgcn_mfma_f32_16x16x32_bf16(af[mi], bfr[ni], acc[mi][ni], 0, 0, 0);
      }
    }
    __syncthreads();
  }

  if (isV) {
#pragma unroll
    for (int a = 0; a < 4; ++a)
#pragma unroll
      for (int c = 0; c < 4; ++c) {
#pragma unroll
        for (int r = 0; r < 4; ++r) {
          int hh   = (bn - 16) * 128 + wc * 64 + a * 16 + g * 4 + r;
          int tokg = bm * 128 + wr * 64 + c * 16 + r16;
          int b_   = tokg >> 11;
          int tok  = tokg & (SEQ - 1);
          int h_   = hh >> 6;
          int d_   = hh & 63;
          VT[((size_t)(b_ * NHEAD + h_) * HD + d_) * SEQ + tok] = f2bf(acc[a][c][r]);
        }
      }
  } else {
#pragma unroll
    for (int mi = 0; mi < 4; ++mi)
#pragma unroll
      for (int ni = 0; ni < 4; ++ni) {
        int row0 = bm * 128 + wr * 64 + mi * 16 + g * 4;
        int col  = bn * 128 + wc * 64 + ni * 16 + r16;
#pragma unroll
        for (int r = 0; r < 4; ++r) {
          float v = acc[mi][ni][r];
          if (BF16OUT) ((u16*)Cv)[(size_t)(row0 + r) * N + col] = f2bf(v);
          else         ((float*)Cv)[(size_t)(row0 + r) * N + col] = v;
        }
      }
  }
}

// ---------------- GEMM: 128x64 tile (O-proj: grid 512 = 2 blocks/CU) ----
__global__ __launch_bounds__(256) void gemm_bt64(const u16* __restrict__ A,
                                                 const u16* __restrict__ B,
                                                 float* __restrict__ C,
                                                 int M, int N, int K) {
  __shared__ u16 At[128 * 64];
  __shared__ u16 Bt[64 * 64];
  const int tid  = threadIdx.x;
  const int wave = tid >> 6;
  const int lane = tid & 63;
  const int g    = lane >> 4;
  const int r16  = lane & 15;
  const int bm   = blockIdx.y;
  const int bn   = blockIdx.x;

  const u16* Ab = A + (size_t)bm * 128 * K;
  const u16* Bb = B + (size_t)bn * 64 * K;
  const int srow = lane >> 3;
  const int scol = (lane & 7) * 8;

  f32x4 acc[2][4] = {};

  for (int kt = 0; kt < K; kt += 64) {
#pragma unroll
    for (int c = 0; c < 4; ++c) {
      int seg = wave * 4 + c;
      gld_lds16(Ab + (size_t)(seg * 8 + srow) * K + kt + scol, &At[seg * 512]);
    }
#pragma unroll
    for (int c = 0; c < 2; ++c) {
      int seg = wave * 2 + c;
      gld_lds16(Bb + (size_t)(seg * 8 + srow) * K + kt + scol, &Bt[seg * 512]);
    }
    __syncthreads();
#pragma unroll
    for (int ko = 0; ko < 64; ko += 32) {
      bf16x8 af[2], bfr[4];
#pragma unroll
      for (int mi = 0; mi < 2; ++mi)
        af[mi] = *reinterpret_cast<const bf16x8*>(&At[(wave * 32 + mi * 16 + r16) * 64 + ko + g * 8]);
#pragma unroll
      for (int ni = 0; ni < 4; ++ni)
        bfr[ni] = *reinterpret_cast<const bf16x8*>(&Bt[(ni * 16 + r16) * 64 + ko + g * 8]);
#pragma unroll
      for (int mi = 0; mi < 2; ++mi)
#pragma unroll
        for (int ni = 0; ni < 4; ++ni)
          acc[mi][ni] = __builtin_amdgcn_mfma_f32_16x16x32_bf16(af[mi], bfr[ni], acc[mi][ni], 0, 0, 0);
    }
    __syncthreads();
  }

#pragma unroll
  for (int mi = 0; mi < 2; ++mi)
#pragma unroll
    for (int ni = 0; ni < 4; ++ni) {
      int row0 = bm * 128 + wave * 32 + mi * 16 + g * 4;
      int col  = bn * 64 + ni * 16 + r16;
#pragma unroll
      for (int r = 0; r < 4; ++r)
        C[(size_t)(row0 + r) * N + col] = acc[mi][ni][r];
    }
}

// ---------------- flash attention (R17 verbatim: gld_lds K+V, 1 barrier/tile) ----
__global__ __launch_bounds__(256, 4) void attn_kernel(const u16* __restrict__ qkv,
                                                      const u16* __restrict__ VT,
                                                      const float* __restrict__ mask,
                                                      u16* __restrict__ AO) {
  __shared__ u16 Kt[2][64 * 64];   // [key][d] swizzled, double-buffered
  __shared__ u16 Vt[2][64 * 64];   // [d][key] swizzled, double-buffered
  __shared__ u16 Pl[4][16 * 64];   // per-wave P swizzled (wave-private)

  const int tid  = threadIdx.x;
  const int w    = tid >> 6;
  const int lane = tid & 63;
  const int g    = lane >> 4;
  const int r16  = lane & 15;

  const int n  = blockIdx.x;
  const int x  = n & 7;
  const int s_ = n >> 3;
  const int h  = s_ & 15;
  const int t_ = ((s_ >> 4) << 3) + x;
  const int b  = t_ >> 5;
  const int qt = t_ & 31;

  const size_t tokbase = (size_t)b * SEQ;
  const u16* VTbh = VT + (size_t)(b * NHEAD + h) * HD * SEQ;

  bf16x8 aq[2];
  {
    int qrow = qt * 64 + w * 16 + r16;
#pragma unroll
    for (int ko = 0; ko < 2; ++ko)
      aq[ko] = *reinterpret_cast<const bf16x8*>(
          qkv + ((tokbase + qrow) * 3 + 0) * HID + h * HD + ko * 32 + g * 8);
  }

  f32x4 o[4] = {};
  float mrow[4], lrow[4];
#pragma unroll
  for (int r = 0; r < 4; ++r) { mrow[r] = -3.0e38f; lrow[r] = 0.f; }

  const int srowK = lane >> 3;        // 0..7

#define STAGE_K(buf, kb)                                                        \
  {                                                                             \
    _Pragma("unroll")                                                           \
    for (int c = 0; c < 2; ++c) {                                               \
      int seg = w * 2 + c;                                                      \
      int sK  = ((seg >> 1) + srowK) & 7;                                       \
      int srcc = (lane & 7) ^ sK;                                               \
      gld_lds16(qkv + ((tokbase + (kb) + seg * 8 + srowK) * 3 + 1) * HID +      \
                    h * HD + srcc * 8,                                          \
                &Kt[buf][seg * 512]);                                           \
    }                                                                           \
  }
#define STAGE_V(buf, kb)                                                        \
  {                                                                             \
    _Pragma("unroll")                                                           \
    for (int c = 0; c < 2; ++c) {                                               \
      int seg = w * 2 + c;                                                      \
      int sV  = ((seg >> 1) + srowK) & 7;                                       \
      int srcc = (lane & 7) ^ sV;                                               \
      gld_lds16(VTbh + (size_t)(seg * 8 + srowK) * SEQ + (kb) + srcc * 8,       \
                &Vt[buf][seg * 512]);                                           \
    }                                                                           \
  }

  // ---- prologue: K+V tile 0 in flight ----
  STAGE_K(0, 0);
  STAGE_V(0, 0);

#pragma unroll 1
  for (int kb = 0; kb < SEQ; kb += 64) {
    const int cur = (kb >> 6) & 1;
    const int nxt = cur ^ 1;
    const bool more = (kb + 64) < SEQ;

    // ---- mask regs for THIS tile ----
    float mpre[4][4];
#pragma unroll
    for (int r = 0; r < 4; ++r) {
      int q = qt * 64 + w * 16 + g * 4 + r;
      const float* mp = mask + ((size_t)b * SEQ + q) * SEQ + kb;
#pragma unroll
      for (int ni = 0; ni < 4; ++ni) mpre[r][ni] = mp[ni * 16 + r16];
    }

    __syncthreads();   // Kt/Vt[cur] + mask landed; all waves done with [nxt] bufs

    // ---- S = Q K^T on Kt[cur] ----
    f32x4 sf[4] = {};
    __builtin_amdgcn_s_setprio(1);
#pragma unroll
    for (int ko = 0; ko < 2; ++ko) {
      bf16x8 bk[4];
#pragma unroll
      for (int ni = 0; ni < 4; ++ni) {
        int row = ni * 16 + r16;
        int sK  = (ni + (r16 & 7)) & 7;
        bk[ni] = *reinterpret_cast<const bf16x8*>(
            &Kt[cur][row * 64 + (((ko * 4 + g) ^ sK) << 3)]);
      }
#pragma unroll
      for (int ni = 0; ni < 4; ++ni)
        sf[ni] = __builtin_amdgcn_mfma_f32_16x16x32_bf16(aq[ko], bk[ni], sf[ni], 0, 0, 0);
    }
    __builtin_amdgcn_s_setprio(0);

    // ---- online softmax: DPP rotate-reduce + defer-max (THR=8) ----
    float mx[4];
#pragma unroll
    for (int r = 0; r < 4; ++r) {
      float m_ = -3.0e38f;
#pragma unroll
      for (int ni = 0; ni < 4; ++ni) {
        float sv = sf[ni][r] * 0.125f + mpre[r][ni];
        sf[ni][r] = sv;
        m_ = fmaxf(m_, sv);
      }
      mx[r] = rowmax16(m_);
    }
    float need = 0.f;
#pragma unroll
    for (int r = 0; r < 4; ++r) need = fmaxf(need, mx[r] - mrow[r]);
    if (__any(need > 8.0f)) {
#pragma unroll
      for (int r = 0; r < 4; ++r) {
        float mnew  = fmaxf(mrow[r], mx[r]);
        float alpha = __expf(mrow[r] - mnew);
        mrow[r] = mnew;
        lrow[r] *= alpha;
#pragma unroll
        for (int di = 0; di < 4; ++di) o[di][r] *= alpha;
      }
    }
#pragma unroll
    for (int r = 0; r < 4; ++r) {
      float p0 = __expf(sf[0][r] - mrow[r]);
      float p1 = __expf(sf[1][r] - mrow[r]);
      float p2 = __expf(sf[2][r] - mrow[r]);
      float p3 = __expf(sf[3][r] - mrow[r]);
      float s  = rowsum16(p0 + p1 + p2 + p3);
      lrow[r] += s;
      unsigned pk01 = cvtpk(p0, p1);
      unsigned pk23 = cvtpk(p2, p3);
      int prow = g * 4 + r;
      int sP   = prow & 7;
      u16 pv[4] = { (u16)pk01, (u16)(pk01 >> 16), (u16)pk23, (u16)(pk23 >> 16) };
#pragma unroll
      for (int ni = 0; ni < 4; ++ni) {
        int chunk = ni * 2 + (r16 >> 3);
        Pl[w][prow * 64 + ((chunk ^ sP) << 3) + (r16 & 7)] = pv[ni];
      }
    }
    // no barrier: Pl[w] is wave-private; lgkmcnt orders write->read

    // ---- prefetch next K+V tiles (zero-register) ----
    if (more) { STAGE_K(nxt, kb + 64); STAGE_V(nxt, kb + 64); }

    // ---- O += P V ----
    __builtin_amdgcn_s_setprio(1);
#pragma unroll
    for (int kk = 0; kk < 2; ++kk) {
      bf16x8 pa, bv[4];
      pa = *reinterpret_cast<const bf16x8*>(
          &Pl[w][r16 * 64 + (((kk * 4 + g) ^ (r16 & 7)) << 3)]);
#pragma unroll
      for (int di = 0; di < 4; ++di) {
        int row = di * 16 + r16;
        int sV  = (di + (r16 & 7)) & 7;
        bv[di] = *reinterpret_cast<const bf16x8*>(
            &Vt[cur][row * 64 + (((kk * 4 + g) ^ sV) << 3)]);
      }
#pragma unroll
      for (int di = 0; di < 4; ++di)
        o[di] = __builtin_amdgcn_mfma_f32_16x16x32_bf16(pa, bv[di], o[di], 0, 0, 0);
    }
    __builtin_amdgcn_s_setprio(0);
  }

  // finalize
#pragma unroll
  for (int di = 0; di < 4; ++di)
#pragma unroll
    for (int r = 0; r < 4; ++r) {
      int srow = qt * 64 + w * 16 + g * 4 + r;
      float val = o[di][r] / lrow[r];
      AO[(tokbase + srow) * HID + h * HD + di * 16 + r16] = f2bf(val);
    }
#undef STAGE_K
#undef STAGE_V
}

// ---------------- launcher ----------------
extern "C" void kernel_launch(void* const* d_in, const int* in_sizes, int n_in,
                              void* d_out, int out_size, void* d_ws, size_t ws_size,
                              hipStream_t stream) {
  (void)in_sizes; (void)n_in; (void)out_size; (void)ws_size;
  const float* hs   = (const float*)d_in[0];
  const float* mask = (const float*)d_in[1];
  const float* wqkv = (const float*)d_in[2];
  const float* wo   = (const float*)d_in[3];
  float* out = (float*)d_out;

  char* ws   = (char*)d_ws;
  u16* Xb    = (u16*)(ws);                        // 8 MiB
  u16* Wqkvb = (u16*)(ws + 8u  * 1024 * 1024);    // 6 MiB
  u16* Wob   = (u16*)(ws + 14u * 1024 * 1024);    // 2 MiB
  u16* QKVb  = (u16*)(ws + 16u * 1024 * 1024);    // 24 MiB (V range unused)
  u16* AOb   = (u16*)(ws + 40u * 1024 * 1024);    // 8 MiB
  u16* VT    = (u16*)(ws + 48u * 1024 * 1024);    // 8 MiB

  cvt3_kernel<<<8192, 256, 0, stream>>>(hs, Xb, wqkv, Wqkvb, wo, Wob);

  gemm_bt<true><<<dim3(3072 / 128, 4096 / 128), 256, 0, stream>>>(Xb, Wqkvb, QKVb, VT, NTOK, 3072, HID);
  attn_kernel  <<<1024, 256, 0, stream>>>(QKVb, VT, mask, AOb);
  gemm_bt64    <<<dim3(1024 / 64, 4096 / 128), 256, 0, stream>>>(AOb, Wob, out, NTOK, 1024, HID);
}